// Round 5
// baseline (106.550 us; speedup 1.0000x reference)
//
#include <hip/hip_runtime.h>
#include <math.h>

// Problem constants (from reference)
constexpr int ROWS = 32768;   // 2*16*1024
constexpr int COLS = 2048;
constexpr int K    = 512;
constexpr float EPS = 1e-5f;
constexpr int WPB  = 4;       // waves per block (1 row per wave)

// clang ext_vector types — required by __builtin_nontemporal_load/store
typedef float f32x4 __attribute__((ext_vector_type(4)));
typedef int   i32x4 __attribute__((ext_vector_type(4)));

// Wave-level LDS fence (wave64 lockstep; each wave owns a private LDS slice,
// so no workgroup barriers anywhere). sched_barrier(0) after the inline-asm
// waitcnt stops hipcc hoisting dependent ops past it (rule #18).
__device__ __forceinline__ void wave_lds_fence() {
    asm volatile("s_waitcnt lgkmcnt(0)" ::: "memory");
    __builtin_amdgcn_sched_barrier(0);
}

// Each wave (64 lanes) owns one row, fully independent of other waves:
//  1. zero its LDS row immediately (no deps — hides under load latency)
//  2. gather 8 values/lane DIRECTLY from global x via col_indices (L2-resident;
//     same HBM lines as full-row staging, but no DMA + no vmcnt(0) full drain)
//  3. wave shfl reductions: mean/var -> normalize -> max -> exp/sum -> softmax
//  4. scatter softmax values into the zeroed LDS row, write out coalesced NT
__global__ __launch_bounds__(256) void fused_gather_ln_softmax_scatter(
    const float* __restrict__ x,
    const float* __restrict__ gamma,
    const float* __restrict__ beta,
    const int*   __restrict__ cidx,
    float*       __restrict__ out)
{
    __shared__ float lds[WPB][COLS];   // 32 KiB (output assembly only)
    const int lane = threadIdx.x & 63;
    const int wv   = threadIdx.x >> 6;
    const int row  = blockIdx.x * WPB + wv;   // grid sized exactly ROWS/WPB

    // ---- zero the output row in LDS right away (no dependencies) ----
    f32x4* l4 = reinterpret_cast<f32x4*>(lds[wv]);
    const f32x4 z4 = (f32x4)(0.f);
    #pragma unroll
    for (int i = 0; i < 8; ++i)
        l4[i * 64 + lane] = z4;

    // ---- load this lane's 8 column indices (coalesced int4 x2, cached) ----
    const i32x4* i4 = reinterpret_cast<const i32x4*>(cidx + (size_t)row * K) + lane * 2;
    const i32x4 ia = i4[0];
    const i32x4 ib = i4[1];
    const int idx[8] = {ia.x, ia.y, ia.z, ia.w, ib.x, ib.y, ib.z, ib.w};

    // ---- gamma/beta for this lane's K-positions (k = lane*8 + j) ----
    const f32x4* g4 = reinterpret_cast<const f32x4*>(gamma) + lane * 2;
    const f32x4* b4 = reinterpret_cast<const f32x4*>(beta)  + lane * 2;
    const f32x4 ga = g4[0], gb = g4[1];
    const f32x4 ba = b4[0], bb = b4[1];
    const float g[8] = {ga.x, ga.y, ga.z, ga.w, gb.x, gb.y, gb.z, gb.w};
    const float b[8] = {ba.x, ba.y, ba.z, ba.w, bb.x, bb.y, bb.z, bb.w};

    // ---- gather directly from global (8 independent loads, L2-resident) ----
    const float* xrow = x + (size_t)row * COLS;
    float v[8];
    #pragma unroll
    for (int j = 0; j < 8; ++j) v[j] = xrow[idx[j]];

    // ---- mean / biased variance over K=512 (wave reduction) ----
    float s = 0.f, ss = 0.f;
    #pragma unroll
    for (int j = 0; j < 8; ++j) { s += v[j]; ss += v[j] * v[j]; }
    #pragma unroll
    for (int off = 32; off >= 1; off >>= 1) {
        s  += __shfl_xor(s,  off, 64);
        ss += __shfl_xor(ss, off, 64);
    }
    const float mu   = s * (1.f / K);
    const float var  = ss * (1.f / K) - mu * mu;
    const float rstd = rsqrtf(var + EPS);

    // ---- normalize + row max ----
    float xn[8];
    float m = -INFINITY;
    #pragma unroll
    for (int j = 0; j < 8; ++j) {
        xn[j] = (v[j] - mu) * rstd * g[j] + b[j];
        m = fmaxf(m, xn[j]);
    }
    #pragma unroll
    for (int off = 32; off >= 1; off >>= 1)
        m = fmaxf(m, __shfl_xor(m, off, 64));

    // ---- exp + sum ----
    float p[8], ps = 0.f;
    #pragma unroll
    for (int j = 0; j < 8; ++j) { p[j] = __expf(xn[j] - m); ps += p[j]; }
    #pragma unroll
    for (int off = 32; off >= 1; off >>= 1)
        ps += __shfl_xor(ps, off, 64);
    const float inv = 1.f / ps;

    // ---- scatter softmax values into the zeroed LDS row ----
    // (per-wave DS ops complete in order: zeros above precede these writes)
    #pragma unroll
    for (int j = 0; j < 8; ++j)
        lds[wv][idx[j]] = p[j] * inv;

    wave_lds_fence();   // zero+scatter visible wave-wide before readback

    // ---- coalesced nontemporal store of the full row ----
    f32x4* o4 = reinterpret_cast<f32x4*>(out + (size_t)row * COLS);
    #pragma unroll
    for (int i = 0; i < 8; ++i)
        __builtin_nontemporal_store(l4[i * 64 + lane], &o4[i * 64 + lane]);
}

extern "C" void kernel_launch(void* const* d_in, const int* in_sizes, int n_in,
                              void* d_out, int out_size, void* d_ws, size_t ws_size,
                              hipStream_t stream) {
    const float* x     = (const float*)d_in[0];
    const float* gamma = (const float*)d_in[1];
    const float* beta  = (const float*)d_in[2];
    const int*   cidx  = (const int*)d_in[3];
    float* out = (float*)d_out;

    dim3 grid(ROWS / WPB);   // 8192 blocks
    dim3 block(256);
    hipLaunchKernelGGL(fused_gather_ln_softmax_scatter, grid, block, 0, stream,
                       x, gamma, beta, cidx, out);
}

// Round 6
// 96.522 us; speedup vs baseline: 1.1039x; 1.1039x over previous
//
#include <hip/hip_runtime.h>
#include <math.h>

// Problem constants (from reference)
constexpr int ROWS = 32768;   // 2*16*1024
constexpr int COLS = 2048;
constexpr int K    = 512;
constexpr float EPS = 1e-5f;
constexpr int WPB  = 2;       // waves per block
constexpr int RPW  = 4;       // rows per wave (pipeline depth)

typedef float f32x4 __attribute__((ext_vector_type(4)));
typedef int   i32x4 __attribute__((ext_vector_type(4)));

__device__ __forceinline__ void sbar() { __builtin_amdgcn_sched_barrier(0); }

// Wave-level LDS fence (wave64 lockstep, private per-wave LDS slice, no
// workgroup barriers anywhere). sched_barrier stops hoisting (rule #18).
__device__ __forceinline__ void lds_fence() {
    asm volatile("s_waitcnt lgkmcnt(0)" ::: "memory");
    __builtin_amdgcn_sched_barrier(0);
}

// Counted vmem wait: N = number of vmem ops issued AFTER the group we need
// retired (vmcnt retires in issue order; extra compiler ops after the group
// only make the wait stricter, never unsafe).
#define VMWAIT(N) do { asm volatile("s_waitcnt vmcnt(" #N ")" ::: "memory"); \
                       __builtin_amdgcn_sched_barrier(0); } while (0)

// Per wave: 4 rows, double-buffered. Pipeline (vmem-op ledger in comments):
//   P : gb(4) idx0(2) DMA0(8)
//   i0: DMA1(8) idx1(2) | W vmcnt(10) | compute0 store0(8)
//   i1: DMA2(8) idx2(2) | W vmcnt(18) | compute1 store1(8)
//   i2: DMA3(8) idx3(2) | W vmcnt(18) | compute2 store2(8)
//   i3:                 | W vmcnt(8)  | compute3 store3(8)
__global__ __launch_bounds__(128) void fused_gather_ln_softmax_scatter(
    const float* __restrict__ x,
    const float* __restrict__ gamma,
    const float* __restrict__ beta,
    const int*   __restrict__ cidx,
    float*       __restrict__ out)
{
    __shared__ float lds[WPB * 2][COLS];   // 2 buffers per wave, 32 KiB total
    const int lane = threadIdx.x & 63;
    const int wv   = threadIdx.x >> 6;
    const int gw   = blockIdx.x * WPB + wv;   // global wave id
    const int row0 = gw * RPW;

    float* bufA = lds[wv * 2 + 0];
    float* bufB = lds[wv * 2 + 1];

    // ---- issue a row's staging DMA: 8 x global_load_lds_dwordx4 ----
    auto dma_row = [&](float* buf, int row) {
        const f32x4* src = reinterpret_cast<const f32x4*>(x + (size_t)row * COLS);
        #pragma unroll
        for (int ii = 0; ii < 8; ++ii)
            __builtin_amdgcn_global_load_lds(
                reinterpret_cast<const unsigned int*>(src + ii * 64 + lane),
                reinterpret_cast<unsigned int*>(buf + ii * 256),
                16, 0, 0);
    };
    // ---- issue a row's index loads (2 vmem ops) ----
    auto idx_load = [&](i32x4& a, i32x4& b, int row) {
        const i32x4* ip = reinterpret_cast<const i32x4*>(cidx + (size_t)row * K) + lane * 2;
        a = __builtin_nontemporal_load(ip);
        b = __builtin_nontemporal_load(ip + 1);
    };

    // ---- prologue: gamma/beta (uniform across this wave's rows), 4 vmem ----
    const f32x4* g4 = reinterpret_cast<const f32x4*>(gamma) + lane * 2;
    const f32x4* b4 = reinterpret_cast<const f32x4*>(beta)  + lane * 2;
    const f32x4 ga = g4[0], gb = g4[1];
    const f32x4 ba = b4[0], bb = b4[1];
    const float g[8] = {ga.x, ga.y, ga.z, ga.w, gb.x, gb.y, gb.z, gb.w};
    const float b[8] = {ba.x, ba.y, ba.z, ba.w, bb.x, bb.y, bb.z, bb.w};

    // ---- compute + output one row from a staged buffer ----
    auto process = [&](float* buf, const i32x4 ia, const i32x4 ib, int row) {
        const int idx[8] = {ia.x, ia.y, ia.z, ia.w, ib.x, ib.y, ib.z, ib.w};
        float v[8];
        #pragma unroll
        for (int j = 0; j < 8; ++j) v[j] = buf[idx[j]];

        float s = 0.f, ss = 0.f;
        #pragma unroll
        for (int j = 0; j < 8; ++j) { s += v[j]; ss += v[j] * v[j]; }
        #pragma unroll
        for (int off = 32; off >= 1; off >>= 1) {
            s  += __shfl_xor(s,  off, 64);
            ss += __shfl_xor(ss, off, 64);
        }
        const float mu   = s * (1.f / K);
        const float var  = ss * (1.f / K) - mu * mu;
        const float rstd = rsqrtf(var + EPS);

        float xn[8];
        float m = -INFINITY;
        #pragma unroll
        for (int j = 0; j < 8; ++j) {
            xn[j] = (v[j] - mu) * rstd * g[j] + b[j];
            m = fmaxf(m, xn[j]);
        }
        #pragma unroll
        for (int off = 32; off >= 1; off >>= 1)
            m = fmaxf(m, __shfl_xor(m, off, 64));

        float p[8], ps = 0.f;
        #pragma unroll
        for (int j = 0; j < 8; ++j) { p[j] = __expf(xn[j] - m); ps += p[j]; }
        #pragma unroll
        for (int off = 32; off >= 1; off >>= 1)
            ps += __shfl_xor(ps, off, 64);
        const float inv = 1.f / ps;

        // zero row then scatter (per-wave DS ops retire in order; compiler
        // keeps may-alias ds order, gather reads above precede these writes)
        f32x4* l4 = reinterpret_cast<f32x4*>(buf);
        const f32x4 z4 = (f32x4)(0.f);
        #pragma unroll
        for (int i = 0; i < 8; ++i) l4[i * 64 + lane] = z4;
        #pragma unroll
        for (int j = 0; j < 8; ++j) buf[idx[j]] = p[j] * inv;

        lds_fence();   // scatter visible wave-wide before readback

        f32x4* o4 = reinterpret_cast<f32x4*>(out + (size_t)row * COLS);
        #pragma unroll
        for (int i = 0; i < 8; ++i)
            __builtin_nontemporal_store(l4[i * 64 + lane], &o4[i * 64 + lane]);
    };

    // ---- software pipeline (vmem ledger in header comment) ----
    i32x4 a0, b0, a1, b1, a2, b2, a3, b3;
    idx_load(a0, b0, row0 + 0);
    dma_row(bufA, row0 + 0);
    sbar();

    dma_row(bufB, row0 + 1); idx_load(a1, b1, row0 + 1); sbar();
    VMWAIT(10);                        // DMA0+idx0 retired
    process(bufA, a0, b0, row0 + 0); sbar();

    dma_row(bufA, row0 + 2); idx_load(a2, b2, row0 + 2); sbar();
    VMWAIT(18);                        // DMA1+idx1 retired (ST0+DMA2+idx2 in flight)
    process(bufB, a1, b1, row0 + 1); sbar();

    dma_row(bufB, row0 + 3); idx_load(a3, b3, row0 + 3); sbar();
    VMWAIT(18);                        // DMA2+idx2 retired (ST1+DMA3+idx3 in flight)
    process(bufA, a2, b2, row0 + 2); sbar();

    VMWAIT(8);                         // DMA3+idx3 retired (ST2 in flight)
    process(bufB, a3, b3, row0 + 3); sbar();
}

extern "C" void kernel_launch(void* const* d_in, const int* in_sizes, int n_in,
                              void* d_out, int out_size, void* d_ws, size_t ws_size,
                              hipStream_t stream) {
    const float* x     = (const float*)d_in[0];
    const float* gamma = (const float*)d_in[1];
    const float* beta  = (const float*)d_in[2];
    const int*   cidx  = (const int*)d_in[3];
    float* out = (float*)d_out;

    dim3 grid(ROWS / (WPB * RPW));   // 4096 blocks
    dim3 block(WPB * 64);            // 128 threads
    hipLaunchKernelGGL(fused_gather_ln_softmax_scatter, grid, block, 0, stream,
                       x, gamma, beta, cidx, out);
}